// Round 17
// baseline (302.878 us; speedup 1.0000x reference)
//
#include <hip/hip_runtime.h>
#include <cstdint>

// ---------- types ----------
typedef __attribute__((ext_vector_type(8))) __bf16  bf8v;   // MFMA A/B operand (4 VGPRs)
typedef __attribute__((ext_vector_type(4))) float   f4v;    // MFMA C/D
typedef __attribute__((ext_vector_type(2))) float   f2v;    // packed f32 pair
typedef __attribute__((ext_vector_type(8))) unsigned short ush8; // 16B staging chunk

__device__ __forceinline__ float bf2f(unsigned short u) {
    union { unsigned u; float f; } v; v.u = ((unsigned)u) << 16; return v.f;
}
// native HW converts (RNE) — compiler emits v_cvt(_pk)_bf16_f32
__device__ __forceinline__ unsigned short f2bf_n(float f) {
    union { __bf16 h; unsigned short s; } v; v.h = (__bf16)f; return v.s;
}
__device__ __forceinline__ unsigned pack2bf(float a, float b) {
    union { __bf16 h[2]; unsigned u; } v;
    v.h[0] = (__bf16)a; v.h[1] = (__bf16)b; return v.u;
}

#define GLDS16(gp, lp)                                                          \
    __builtin_amdgcn_global_load_lds(                                           \
        (const __attribute__((address_space(1))) void*)(uintptr_t)(gp),         \
        (__attribute__((address_space(3))) void*)(uintptr_t)(lp), 16, 0, 0)

// ---------- fused prep: X cast (blocks 0..4095) + 4 weight transposes ----------
__global__ void prep_all(const float* __restrict__ hs, unsigned short* __restrict__ Xb,
                         const float* __restrict__ wq, const float* __restrict__ wk,
                         const float* __restrict__ wv, const float* __restrict__ wo,
                         unsigned short* __restrict__ Wqkv, unsigned short* __restrict__ Wot) {
    const int blk = blockIdx.x;
    if (blk < 4096) {                    // ---- cast X fp32 -> bf16, 8 elems/thread
        int i = blk * 256 + threadIdx.x;
        float4 a = ((const float4*)hs)[2 * i];
        float4 b = ((const float4*)hs)[2 * i + 1];
        uint4 o;
        o.x = pack2bf(a.x, a.y);
        o.y = pack2bf(a.z, a.w);
        o.z = pack2bf(b.x, b.y);
        o.w = pack2bf(b.z, b.w);
        ((uint4*)Xb)[i] = o;
        return;                          // block-uniform branch: no barrier hazard
    }
    const float* in;
    unsigned short* out;
    int C, bx, by;
    if (blk < 8192)       { int z = blk - 4096;  in = wq; out = Wqkv;           C = 2048; bx = z & 63; by = z >> 6; }
    else if (blk < 9216)  { int z = blk - 8192;  in = wk; out = Wqkv + 4194304; C = 512;  bx = z & 15; by = z >> 4; }
    else if (blk < 10240) { int z = blk - 9216;  in = wv; out = Wqkv + 5242880; C = 512;  bx = z & 15; by = z >> 4; }
    else                  { int z = blk - 10240; in = wo; out = Wot;            C = 2048; bx = z & 63; by = z >> 6; }
    __shared__ float t[32][33];
    const int c0 = bx * 32, r0 = by * 32;
    const int x = threadIdx.x & 31, y = threadIdx.x >> 5;   // (32,8) layout
    #pragma unroll
    for (int i = 0; i < 32; i += 8) t[y + i][x] = in[(size_t)(r0 + y + i) * C + c0 + x];
    __syncthreads();
    #pragma unroll
    for (int i = 0; i < 32; i += 8)
        out[(size_t)(c0 + y + i) * 2048 + r0 + x] = f2bf_n(t[x][y + i]);   // R = 2048 always
}

// ---------- fused: K RoPE (blocks 0..4095) + V transpose (blocks 4096..6143) ----------
__global__ void rope_tv(unsigned short* __restrict__ QKV,
                        const int* __restrict__ pos_ids,
                        float* __restrict__ kpart,
                        unsigned short* __restrict__ VtG) {
    const int blk = blockIdx.x;
    if (blk < 4096) {
        // ---- K RoPE in place (8 kv heads, stride 3072, coloff 2048) ----
        int idx = blk * 256 + threadIdx.x;
        int i   = idx & 31;                   // pair index (D/2 = 32)
        int hh  = (idx >> 5) & 7;             // nh_log2 = 3
        int tok = idx >> 8;
        int pos = pos_ids[tok];
        float ang = (float)pos * exp2f(-0.41524101186092f * (float)i);
        float s = sinf(ang), c = cosf(ang);
        unsigned short* p = QKV + (size_t)tok * 3072 + 2048 + hh * 64 + 2 * i;
        unsigned pr = *(const unsigned*)p;
        float xr = bf2f((unsigned short)(pr & 0xffff));
        float xi = bf2f((unsigned short)(pr >> 16));
        float orr = xr * c - xi * s;
        float oi  = xr * s + xi * c;
        *(unsigned*)p = pack2bf(orr, oi);
        // per-wave max|K| -> plain store (NO same-address atomics: r9 lesson)
        float loc = fmaxf(fabsf(orr), fabsf(oi));
        #pragma unroll
        for (int off = 1; off < 64; off <<= 1) loc = fmaxf(loc, __shfl_xor(loc, off));
        if ((threadIdx.x & 63) == 0) kpart[blk * 4 + (threadIdx.x >> 6)] = loc;
        return;
    }
    // ---- V transpose with key-group XOR permutation: [4096][3072]@2560 -> [512][4096]
    __shared__ unsigned short t[32][33];
    const int z = blk - 4096;                 // grid was (16,128)
    const int c0 = (z & 15) * 32;             // v-col d
    const int r0 = (z >> 4) * 32;             // token
    const int x = threadIdx.x & 31, y = threadIdx.x >> 5;
    #pragma unroll
    for (int i = 0; i < 32; i += 8)
        t[y + i][x] = QKV[(size_t)(r0 + y + i) * 3072 + 2560 + c0 + x];
    __syncthreads();
    #pragma unroll
    for (int i = 0; i < 32; i += 8) {
        int d   = c0 + y + i;
        int tok = r0 + x;
        int g   = (tok >> 2) & 15;
        int tp  = (tok & ~63) | (((g ^ (d & 15)) << 2)) | (tok & 3);
        VtG[(size_t)d * 4096 + tp] = t[x][y + i];
    }
}

// ---------- single-block reduce of 16384 partial maxima -> kmax scalar ----------
__global__ void reduce_kmax(const float* __restrict__ kpart,
                            unsigned* __restrict__ kmax_out) {
    float loc = 0.f;
    #pragma unroll
    for (int i = 0; i < 16; ++i) {
        float4 v = ((const float4*)kpart)[i * 256 + threadIdx.x];
        loc = fmaxf(loc, fmaxf(fmaxf(v.x, v.y), fmaxf(v.z, v.w)));
    }
    #pragma unroll
    for (int off = 1; off < 64; off <<= 1) loc = fmaxf(loc, __shfl_xor(loc, off));
    __shared__ float warr[4];
    if ((threadIdx.x & 63) == 0) warr[threadIdx.x >> 6] = loc;
    __syncthreads();
    if (threadIdx.x == 0)
        *kmax_out = __float_as_uint(fmaxf(fmaxf(warr[0], warr[1]),
                                          fmaxf(warr[2], warr[3])));
}

// ---------- GEMM: C[M][N] = A[M][K] * Bt[N][K]^T  (bf16 in, fp32 acc) ----------
template <int OUT_BF16>
__global__ __launch_bounds__(256) void gemm_bt(const unsigned short* __restrict__ A,
                                               const unsigned short* __restrict__ Bt,
                                               void* __restrict__ Cv, int N, int K) {
    __shared__ __align__(16) unsigned short As[128 * 64];
    __shared__ __align__(16) unsigned short Bs[128 * 64];
    const int t = threadIdx.x;
    const int lane = t & 63, w = t >> 6;
    const int wr = w >> 1, wc = w & 1;
    const int lr = lane & 15, lh = lane >> 4;
    const int m0 = blockIdx.y * 128, n0 = blockIdx.x * 128;

    f4v acc[4][4];
    #pragma unroll
    for (int i = 0; i < 4; ++i)
        #pragma unroll
        for (int j = 0; j < 4; ++j) acc[i][j] = f4v{0.f, 0.f, 0.f, 0.f};

    const int o_t = t * 16;
    for (int k0 = 0; k0 < K; k0 += 64) {
        __syncthreads();
        #pragma unroll
        for (int s = 0; s < 4; ++s) {
            int o = s * 4096 + o_t;          // linear LDS byte offset
            int row = o >> 7;
            int src = (o & 127) ^ ((row & 7) << 4);   // inverse-swizzled src col (bytes)
            const unsigned short* gA = A + (size_t)(m0 + row) * K + k0 + (src >> 1);
            GLDS16(gA, As + (o >> 1));
            const unsigned short* gB = Bt + (size_t)(n0 + row) * K + k0 + (src >> 1);
            GLDS16(gB, Bs + (o >> 1));
        }
        __syncthreads();
        #pragma unroll
        for (int kk = 0; kk < 2; ++kk) {
            bf8v af[4], bfr[4];
            #pragma unroll
            for (int mi = 0; mi < 4; ++mi) {
                int row = wr * 64 + mi * 16 + lr;
                int col = (kk * 32 + lh * 8) ^ ((row & 7) << 3);
                af[mi] = *(const bf8v*)(As + row * 64 + col);
            }
            #pragma unroll
            for (int ni = 0; ni < 4; ++ni) {
                int row = wc * 64 + ni * 16 + lr;
                int col = (kk * 32 + lh * 8) ^ ((row & 7) << 3);
                bfr[ni] = *(const bf8v*)(Bs + row * 64 + col);
            }
            #pragma unroll
            for (int mi = 0; mi < 4; ++mi)
                #pragma unroll
                for (int ni = 0; ni < 4; ++ni)
                    acc[mi][ni] = __builtin_amdgcn_mfma_f32_16x16x32_bf16(
                        af[mi], bfr[ni], acc[mi][ni], 0, 0, 0);
        }
    }
    #pragma unroll
    for (int mi = 0; mi < 4; ++mi)
        #pragma unroll
        for (int ni = 0; ni < 4; ++ni)
            #pragma unroll
            for (int r = 0; r < 4; ++r) {
                int row = m0 + wr * 64 + mi * 16 + lh * 4 + r;
                int col = n0 + wc * 64 + ni * 16 + lr;
                float v = acc[mi][ni][r];
                if (OUT_BF16) ((unsigned short*)Cv)[(size_t)row * N + col] = f2bf_n(v);
                else          ((float*)Cv)[(size_t)row * N + col] = v;
            }
}

// ---------- flash attention v13: v12 + 3 blocks/CU ----------
// VGPR=64 and LDS=32KB both allow 3 blocks/CU (96KB LDS, reg cap 512/6=85);
// launch_bounds(512,6) raises occupancy 16 -> 24 waves/CU for latency hiding.
// PV via 16x16x32 logical-k relabel (r16, issue-count halved vs 16x16x16).
__global__ __launch_bounds__(512, 6) void flash_attn(
        const unsigned short* __restrict__ QKV,   // [4096][3072] (Q|K|V cols), K roped
        const unsigned short* __restrict__ VtG,   // [512][4096], group-permuted
        const int* __restrict__ amask,
        const int* __restrict__ pos_ids,
        const unsigned* __restrict__ kmaxp,
        unsigned short* __restrict__ O) {         // [4096][2048]
    __shared__ __align__(16) unsigned short Ks[2][64 * 64];   // K[key][d], swizzled
    __shared__ __align__(16) unsigned short Vs[2][64 * 64];   // V^T[d][key-perm]

    const int t = threadIdx.x, lane = t & 63, w = t >> 6;
    const int lr = lane & 15, lh = lane >> 4;
    const int qsel = w >> 2, w4 = w & 3;
    const int pair = blockIdx.x, h = blockIdx.y, b = blockIdx.z;
    const size_t tok0 = (size_t)b * 2048;

    const unsigned short* Kb = QKV + tok0 * 3072 + 2048 + (h >> 2) * 64;    // row stride 3072
    const unsigned short* Vb = VtG + (size_t)((h >> 2) * 64) * 4096 + tok0; // row stride 4096
    const int* amrow = amask + b * 2048;
    const float kmax = __uint_as_float(*kmaxp);

// 512 threads stage one 64x64 K tile + one 64x64 V tile: 1 chunk each
#define STAGE(buf, kt)                                                              \
    {   int c_ = t;                                                                 \
        int row_ = c_ >> 3;                                                         \
        int sc_ = (((c_ & 7) * 16) ^ ((row_ & 7) << 4)) >> 1;                       \
        GLDS16(Kb + (size_t)((kt) * 64 + row_) * 3072 + sc_, Ks[buf] + c_ * 8);     \
        GLDS16(Vb + (size_t)row_ * 4096 + (kt) * 64 + (c_ & 7) * 8,                 \
               Vs[buf] + c_ * 8);                                                   \
    }

    const float SCL = 0.18033688011112042f;  // (1/sqrt(64)) * log2(e)
    union O8 { bf8v v; unsigned u[4]; };
    O8 ones8;
    ones8.u[0] = ones8.u[1] = ones8.u[2] = ones8.u[3] = 0x3f803f80u;  // 8 x bf16 1.0
    const f4v zf = f4v{0.f, 0.f, 0.f, 0.f};             // hoisted MFMA C=0

    // ---- per-tile aliveness mask, in registers (wave-uniform; no LDS) ----
    unsigned aliveMaskV = 0;
    {
        const int4* am4 = (const int4*)amrow;   // 512 int4s; int4 i covers keys 4i..4i+3
        #pragma unroll
        for (int s = 0; s < 8; ++s) {
            int4 a = am4[s * 64 + lane];
            unsigned long long bal = __ballot(a.x && a.y && a.z && a.w);
            #pragma unroll
            for (int g = 0; g < 4; ++g)
                aliveMaskV |= (((bal >> (16 * g)) & 0xFFFFull) == 0xFFFFull)
                                  ? (1u << (4 * s + g)) : 0u;
        }
    }
    const int aliveMask = __builtin_amdgcn_readfirstlane((int)aliveMaskV);

    // V-read columns (shorts): key-group (kf*4+lh) at permuted position ^lr
    int vcol[4];
    #pragma unroll
    for (int kf = 0; kf < 4; ++kf) vcol[kf] = ((kf * 4 + lh) ^ lr) * 4;

    int cur = 0;
    STAGE(cur, 0);      // tile 0 (shared by both halves' first iteration)

    #pragma unroll 1
    for (int half = 0; half < 2; ++half) {
        const int sj = half ? (15 - pair) : pair;   // super-tile (128 q-rows)
        const int q0 = sj * 128;
        const int nkv = 2 * sj + 2;                 // KV tiles 0..2sj+1
        const int qtw = 2 * sj + qsel;              // this wave's diagonal KV tile
        const int qloc = w4 * 16 + lr;              // q row within wave's 64-row tile

        // ---- load Q row, RoPE in-register (fp32), fold SCL, back to bf16 ----
        const unsigned short* Qp = QKV + (tok0 + q0 + qsel * 64 + qloc) * 3072 + h * 64;
        union Q8 { bf8v v; unsigned short s[8]; } qa0u, qa1u;
        qa0u.v = *(const bf8v*)(Qp + lh * 8);
        qa1u.v = *(const bf8v*)(Qp + 32 + lh * 8);
        float qrmax = 0.f;
        {
            int pos = pos_ids[tok0 + q0 + qsel * 64 + qloc];
            #pragma unroll
            for (int r = 0; r < 4; ++r) {
                float i0 = (float)(lh * 4 + r);
                float ang0 = (float)pos * exp2f(-0.41524101186092f * i0);
                float sn = sinf(ang0), cs = cosf(ang0);
                float xr = bf2f(qa0u.s[2 * r]), xi = bf2f(qa0u.s[2 * r + 1]);
                float a0 = (xr * cs - xi * sn) * SCL, a1 = (xr * sn + xi * cs) * SCL;
                qa0u.s[2 * r]     = f2bf_n(a0);
                qa0u.s[2 * r + 1] = f2bf_n(a1);
                float i1 = (float)(16 + lh * 4 + r);
                float ang1 = (float)pos * exp2f(-0.41524101186092f * i1);
                float sn1 = sinf(ang1), cs1 = cosf(ang1);
                float yr = bf2f(qa1u.s[2 * r]), yi = bf2f(qa1u.s[2 * r + 1]);
                float b0 = (yr * cs1 - yi * sn1) * SCL, b1 = (yr * sn1 + yi * cs1) * SCL;
                qa1u.s[2 * r]     = f2bf_n(b0);
                qa1u.s[2 * r + 1] = f2bf_n(b1);
                qrmax = fmaxf(qrmax, fmaxf(fmaxf(fabsf(a0), fabsf(a1)),
                                           fmaxf(fabsf(b0), fabsf(b1))));
            }
        }
        const bf8v qa0 = qa0u.v, qa1 = qa1u.v;
        // per-q-row score bound: |sa| <= 64 * max|q'| * max|K| (with margins)
        qrmax = fmaxf(qrmax, __shfl_xor(qrmax, 16));
        qrmax = fmaxf(qrmax, __shfl_xor(qrmax, 32));
        const bool safe = __all(64.0f * qrmax * kmax * 1.02f < 80.0f);

        f4v oacc[4];
        #pragma unroll
        for (int i = 0; i < 4; ++i) oacc[i] = f4v{0.f, 0.f, 0.f, 0.f};
        f4v lacc = f4v{0.f, 0.f, 0.f, 0.f};
        float m_ = 0.f;
        f4v sa[4];

        // S^T = K Q^T into sa (reads Ks[curb]); C=0 via hoisted zf (no re-zero)
        auto qk = [&](int curb) {
            __builtin_amdgcn_s_setprio(1);
            #pragma unroll
            for (int kf = 0; kf < 4; ++kf) {
                const unsigned short* Krow = Ks[curb] + (kf * 16 + lr) * 64;
                int swz = (lr & 7) << 3;
                bf8v kb0 = *(const bf8v*)(Krow + ((lh * 8) ^ swz));
                f4v s0 = __builtin_amdgcn_mfma_f32_16x16x32_bf16(kb0, qa0, zf, 0, 0, 0);
                bf8v kb1 = *(const bf8v*)(Krow + ((32 + lh * 8) ^ swz));
                sa[kf] = __builtin_amdgcn_mfma_f32_16x16x32_bf16(kb1, qa1, s0, 0, 0, 0);
            }
            __builtin_amdgcn_s_setprio(0);
        };

        // pack pe per 32-key window, accumulate l via ones-MFMA, PV (16x16x32)
        auto pv = [&](int curb, float pe[4][4]) {
            __builtin_amdgcn_s_setprio(1);
            #pragma unroll
            for (int wdw = 0; wdw < 2; ++wdw) {
                union P8 { bf8v v; unsigned u[4]; } pa;
                pa.u[0] = pack2bf(pe[2 * wdw][0], pe[2 * wdw][1]);
                pa.u[1] = pack2bf(pe[2 * wdw][2], pe[2 * wdw][3]);
                pa.u[2] = pack2bf(pe[2 * wdw + 1][0], pe[2 * wdw + 1][1]);
                pa.u[3] = pack2bf(pe[2 * wdw + 1][2], pe[2 * wdw + 1][3]);
                lacc = __builtin_amdgcn_mfma_f32_16x16x32_bf16(pa.v, ones8.v, lacc, 0, 0, 0);
                #pragma unroll
                for (int df = 0; df < 4; ++df) {
                    const unsigned short* Vrow = Vs[curb] + (df * 16 + lr) * 64;
                    union V8 { bf8v v; uint2 u2[2]; } vb;
                    vb.u2[0] = *(const uint2*)(Vrow + vcol[2 * wdw]);
                    vb.u2[1] = *(const uint2*)(Vrow + vcol[2 * wdw + 1]);
                    oacc[df] = __builtin_amdgcn_mfma_f32_16x16x32_bf16(
                        pa.v, vb.v, oacc[df], 0, 0, 0);
                }
            }
            __builtin_amdgcn_s_setprio(0);
        };

        auto softmax_pv = [&](int curb) {
            float pe[4][4];
            if (__builtin_expect(safe, 1)) {
                // fast: no subtraction, no max logic, no reductions
                #pragma unroll
                for (int kf = 0; kf < 4; ++kf)
                    #pragma unroll
                    for (int r = 0; r < 4; ++r)
                        pe[kf][r] = exp2f(sa[kf][r]);
            } else {
                // slow: lazy-rescale (guarded by row-sum overflow)
                #pragma unroll 1
                for (;;) {
                    #pragma unroll
                    for (int kf = 0; kf < 4; ++kf)
                        #pragma unroll
                        for (int r = 0; r < 4; ++r)
                            pe[kf][r] = exp2f(sa[kf][r] - m_);
                    f2v v0 = f2v{pe[0][0], pe[0][1]} + f2v{pe[0][2], pe[0][3]};
                    f2v v1 = f2v{pe[1][0], pe[1][1]} + f2v{pe[1][2], pe[1][3]};
                    f2v v2 = f2v{pe[2][0], pe[2][1]} + f2v{pe[2][2], pe[2][3]};
                    f2v v3 = f2v{pe[3][0], pe[3][1]} + f2v{pe[3][2], pe[3][3]};
                    f2v vv = (v0 + v1) + (v2 + v3);
                    float rs = vv[0] + vv[1];
                    rs += __shfl_xor(rs, 16);
                    rs += __shfl_xor(rs, 32);
                    if (!__any(rs > 16777216.0f)) break;
                    float t0 = fmaxf(fmaxf(sa[0][0], sa[0][1]), fmaxf(sa[0][2], sa[0][3]));
                    float t1 = fmaxf(fmaxf(sa[1][0], sa[1][1]), fmaxf(sa[1][2], sa[1][3]));
                    float t2 = fmaxf(fmaxf(sa[2][0], sa[2][1]), fmaxf(sa[2][2], sa[2][3]));
                    float t3 = fmaxf(fmaxf(sa[3][0], sa[3][1]), fmaxf(sa[3][2], sa[3][3]));
                    float mx = fmaxf(fmaxf(t0, t1), fmaxf(t2, t3));
                    mx = fmaxf(mx, __shfl_xor(mx, 16));
                    mx = fmaxf(mx, __shfl_xor(mx, 32));
                    float mn = fmaxf(m_, mx);
                    float fac = exp2f(m_ - mn);
                    m_ = mn;
                    float facr[4];
                    #pragma unroll
                    for (int r = 0; r < 4; ++r) facr[r] = __shfl(fac, lh * 4 + r);
                    lacc[0] *= facr[0]; lacc[1] *= facr[1];
                    lacc[2] *= facr[2]; lacc[3] *= facr[3];
                    #pragma unroll
                    for (int df = 0; df < 4; ++df) {
                        f4v o = oacc[df];
                        o[0] *= facr[0]; o[1] *= facr[1]; o[2] *= facr[2]; o[3] *= facr[3];
                        oacc[df] = o;
                    }
                }
            }
            pv(curb, pe);
        };

        __syncthreads();   // tile (cur) staged & previous reads done

        // ---- KV loop over tiles 0..2sj+1 ----
        #pragma unroll 1
        for (int kt = 0; kt < nkv; ++kt) {
            if (kt + 1 < nkv) STAGE(cur ^ 1, kt + 1)
            else if (half == 0) STAGE(cur ^ 1, 0)     // cross-half tile-0 prefetch

            if (kt <= qtw) {                          // wave-uniform branch
                qk(cur);
                if (kt == qtw) {
                    // diagonal tile for this wave (causal + padding)
                    if ((aliveMask >> kt) & 1) {
                        #pragma unroll
                        for (int kf = 0; kf < 4; ++kf)
                            #pragma unroll
                            for (int r = 0; r < 4; ++r) {
                                int keyl = kf * 16 + lh * 4 + r;
                                if (keyl > qloc) sa[kf][r] = -1e30f;
                            }
                    } else {
                        #pragma unroll
                        for (int kf = 0; kf < 4; ++kf) {
                            int4 aq = *(const int4*)(amrow + kt * 64 + kf * 16 + lh * 4);
                            #pragma unroll
                            for (int r = 0; r < 4; ++r) {
                                int keyl = kf * 16 + lh * 4 + r;
                                int am = r == 0 ? aq.x : r == 1 ? aq.y : r == 2 ? aq.z : aq.w;
                                if (am == 0 || keyl > qloc) sa[kf][r] = -1e30f;
                            }
                        }
                    }
                } else if (!((aliveMask >> kt) & 1)) {   // rare: padding mask
                    #pragma unroll
                    for (int kf = 0; kf < 4; ++kf) {
                        int4 aq = *(const int4*)(amrow + kt * 64 + kf * 16 + lh * 4);
                        if (aq.x == 0) sa[kf][0] = -1e30f;
                        if (aq.y == 0) sa[kf][1] = -1e30f;
                        if (aq.z == 0) sa[kf][2] = -1e30f;
                        if (aq.w == 0) sa[kf][3] = -1e30f;
                    }
                }
                softmax_pv(cur);
            }

            __syncthreads();   // drains prefetch vmcnt + joins waves
            cur ^= 1;
        }

        // ---- epilogue: normalize, write bf16 [tok][2048] ----
        // lacc rows == oacc rows (q = lh*4+r) -> no cross-lane redistribution
        float invr[4];
        #pragma unroll
        for (int r = 0; r < 4; ++r) invr[r] = 1.0f / lacc[r];
        #pragma unroll
        for (int df = 0; df < 4; ++df)
            #pragma unroll
            for (int r = 0; r < 4; ++r) {
                int qg = q0 + qsel * 64 + w4 * 16 + lh * 4 + r;
                float v = oacc[df][r] * invr[r];
                O[(tok0 + qg) * 2048 + h * 64 + df * 16 + lr] = f2bf_n(v);
            }
    }
#undef STAGE
}

// ---------- launch ----------
extern "C" void kernel_launch(void* const* d_in, const int* in_sizes, int n_in,
                              void* d_out, int out_size, void* d_ws, size_t ws_size,
                              hipStream_t stream) {
    const float* hs   = (const float*)d_in[0];
    const int* amask  = (const int*)d_in[1];
    const int* pos    = (const int*)d_in[2];
    const float* wq   = (const float*)d_in[3];
    const float* wk   = (const float*)d_in[4];
    const float* wv   = (const float*)d_in[5];
    const float* wo   = (const float*)d_in[6];

    char* ws = (char*)d_ws;
    unsigned short* Xb   = (unsigned short*)(ws);             // 16,777,216 B
    unsigned short* Wqkv = (unsigned short*)(ws + 16777216);  // 12,582,912  [3072][2048]
    unsigned short* Wot  = (unsigned short*)(ws + 29360128);  //  8,388,608
    unsigned short* AOb  = (unsigned short*)(ws + 37748736);  // 16,777,216 (ends 54,525,952)
    unsigned* kmaxp      = (unsigned*)(ws);                   // reuses Xb (dead after QKV gemm)
    float* kpart         = (float*)(ws + 1024);               // 16384 floats, also in dead Xb

    // QKV bf16 [4096][3072] + VtG [512][4096] live inside d_out (dead before final GEMM)
    char* ob = (char*)d_out;
    unsigned short* QKV = (unsigned short*)ob;                // 25,165,824
    unsigned short* VtG = (unsigned short*)(ob + 25165824);   //  4,194,304 (ends 29,360,128)

    // fused prep: X cast + 4 weight transposes in one launch
    prep_all<<<14336, 256, 0, stream>>>(hs, Xb, wq, wk, wv, wo, Wqkv, Wot);

    // fused QKV projection: [4096][3072]
    gemm_bt<1><<<dim3(24, 32), 256, 0, stream>>>(Xb, Wqkv, (void*)QKV, 3072, 2048);

    // fused: K RoPE (per-wave max -> kpart) + V transpose (independent columns)
    rope_tv<<<6144, 256, 0, stream>>>(QKV, pos, kpart, VtG);
    reduce_kmax<<<1, 256, 0, stream>>>(kpart, kmaxp);

    flash_attn<<<dim3(8, 32, 2), 512, 0, stream>>>(QKV, VtG, amask, pos, kmaxp, AOb);

    gemm_bt<0><<<dim3(16, 32), 256, 0, stream>>>(AOb, Wot, d_out, 2048, 2048);
}

// Round 18
// 207.836 us; speedup vs baseline: 1.4573x; 1.4573x over previous
//
#include <hip/hip_runtime.h>
#include <cstdint>

// ---------- types ----------
typedef __attribute__((ext_vector_type(8))) __bf16  bf8v;   // MFMA A/B operand (4 VGPRs)
typedef __attribute__((ext_vector_type(4))) float   f4v;    // MFMA C/D
typedef __attribute__((ext_vector_type(2))) float   f2v;    // packed f32 pair
typedef __attribute__((ext_vector_type(8))) unsigned short ush8; // 16B staging chunk

__device__ __forceinline__ float bf2f(unsigned short u) {
    union { unsigned u; float f; } v; v.u = ((unsigned)u) << 16; return v.f;
}
// native HW converts (RNE) — compiler emits v_cvt(_pk)_bf16_f32
__device__ __forceinline__ unsigned short f2bf_n(float f) {
    union { __bf16 h; unsigned short s; } v; v.h = (__bf16)f; return v.s;
}
__device__ __forceinline__ unsigned pack2bf(float a, float b) {
    union { __bf16 h[2]; unsigned u; } v;
    v.h[0] = (__bf16)a; v.h[1] = (__bf16)b; return v.u;
}

#define GLDS16(gp, lp)                                                          \
    __builtin_amdgcn_global_load_lds(                                           \
        (const __attribute__((address_space(1))) void*)(uintptr_t)(gp),         \
        (__attribute__((address_space(3))) void*)(uintptr_t)(lp), 16, 0, 0)

// ---------- fused prep: X cast (blocks 0..4095) + 4 weight transposes ----------
__global__ void prep_all(const float* __restrict__ hs, unsigned short* __restrict__ Xb,
                         const float* __restrict__ wq, const float* __restrict__ wk,
                         const float* __restrict__ wv, const float* __restrict__ wo,
                         unsigned short* __restrict__ Wqkv, unsigned short* __restrict__ Wot) {
    const int blk = blockIdx.x;
    if (blk < 4096) {                    // ---- cast X fp32 -> bf16, 8 elems/thread
        int i = blk * 256 + threadIdx.x;
        float4 a = ((const float4*)hs)[2 * i];
        float4 b = ((const float4*)hs)[2 * i + 1];
        uint4 o;
        o.x = pack2bf(a.x, a.y);
        o.y = pack2bf(a.z, a.w);
        o.z = pack2bf(b.x, b.y);
        o.w = pack2bf(b.z, b.w);
        ((uint4*)Xb)[i] = o;
        return;                          // block-uniform branch: no barrier hazard
    }
    const float* in;
    unsigned short* out;
    int C, bx, by;
    if (blk < 8192)       { int z = blk - 4096;  in = wq; out = Wqkv;           C = 2048; bx = z & 63; by = z >> 6; }
    else if (blk < 9216)  { int z = blk - 8192;  in = wk; out = Wqkv + 4194304; C = 512;  bx = z & 15; by = z >> 4; }
    else if (blk < 10240) { int z = blk - 9216;  in = wv; out = Wqkv + 5242880; C = 512;  bx = z & 15; by = z >> 4; }
    else                  { int z = blk - 10240; in = wo; out = Wot;            C = 2048; bx = z & 63; by = z >> 6; }
    __shared__ float t[32][33];
    const int c0 = bx * 32, r0 = by * 32;
    const int x = threadIdx.x & 31, y = threadIdx.x >> 5;   // (32,8) layout
    #pragma unroll
    for (int i = 0; i < 32; i += 8) t[y + i][x] = in[(size_t)(r0 + y + i) * C + c0 + x];
    __syncthreads();
    #pragma unroll
    for (int i = 0; i < 32; i += 8)
        out[(size_t)(c0 + y + i) * 2048 + r0 + x] = f2bf_n(t[x][y + i]);   // R = 2048 always
}

// ---------- fused: K RoPE (blocks 0..4095) + V transpose (blocks 4096..6143) ----------
__global__ void rope_tv(unsigned short* __restrict__ QKV,
                        const int* __restrict__ pos_ids,
                        float* __restrict__ kpart,
                        unsigned short* __restrict__ VtG) {
    const int blk = blockIdx.x;
    if (blk < 4096) {
        // ---- K RoPE in place (8 kv heads, stride 3072, coloff 2048) ----
        int idx = blk * 256 + threadIdx.x;
        int i   = idx & 31;                   // pair index (D/2 = 32)
        int hh  = (idx >> 5) & 7;             // nh_log2 = 3
        int tok = idx >> 8;
        int pos = pos_ids[tok];
        float ang = (float)pos * exp2f(-0.41524101186092f * (float)i);
        float s = sinf(ang), c = cosf(ang);
        unsigned short* p = QKV + (size_t)tok * 3072 + 2048 + hh * 64 + 2 * i;
        unsigned pr = *(const unsigned*)p;
        float xr = bf2f((unsigned short)(pr & 0xffff));
        float xi = bf2f((unsigned short)(pr >> 16));
        float orr = xr * c - xi * s;
        float oi  = xr * s + xi * c;
        *(unsigned*)p = pack2bf(orr, oi);
        // per-wave max|K| -> plain store (NO same-address atomics: r9 lesson)
        float loc = fmaxf(fabsf(orr), fabsf(oi));
        #pragma unroll
        for (int off = 1; off < 64; off <<= 1) loc = fmaxf(loc, __shfl_xor(loc, off));
        if ((threadIdx.x & 63) == 0) kpart[blk * 4 + (threadIdx.x >> 6)] = loc;
        return;
    }
    // ---- V transpose with key-group XOR permutation: [4096][3072]@2560 -> [512][4096]
    __shared__ unsigned short t[32][33];
    const int z = blk - 4096;                 // grid was (16,128)
    const int c0 = (z & 15) * 32;             // v-col d
    const int r0 = (z >> 4) * 32;             // token
    const int x = threadIdx.x & 31, y = threadIdx.x >> 5;
    #pragma unroll
    for (int i = 0; i < 32; i += 8)
        t[y + i][x] = QKV[(size_t)(r0 + y + i) * 3072 + 2560 + c0 + x];
    __syncthreads();
    #pragma unroll
    for (int i = 0; i < 32; i += 8) {
        int d   = c0 + y + i;
        int tok = r0 + x;
        int g   = (tok >> 2) & 15;
        int tp  = (tok & ~63) | (((g ^ (d & 15)) << 2)) | (tok & 3);
        VtG[(size_t)d * 4096 + tp] = t[x][y + i];
    }
}

// ---------- single-block reduce of 16384 partial maxima -> kmax scalar ----------
__global__ void reduce_kmax(const float* __restrict__ kpart,
                            unsigned* __restrict__ kmax_out) {
    float loc = 0.f;
    #pragma unroll
    for (int i = 0; i < 16; ++i) {
        float4 v = ((const float4*)kpart)[i * 256 + threadIdx.x];
        loc = fmaxf(loc, fmaxf(fmaxf(v.x, v.y), fmaxf(v.z, v.w)));
    }
    #pragma unroll
    for (int off = 1; off < 64; off <<= 1) loc = fmaxf(loc, __shfl_xor(loc, off));
    __shared__ float warr[4];
    if ((threadIdx.x & 63) == 0) warr[threadIdx.x >> 6] = loc;
    __syncthreads();
    if (threadIdx.x == 0)
        *kmax_out = __float_as_uint(fmaxf(fmaxf(warr[0], warr[1]),
                                          fmaxf(warr[2], warr[3])));
}

// ---------- GEMM: C[M][N] = A[M][K] * Bt[N][K]^T  (bf16 in, fp32 acc) ----------
template <int OUT_BF16>
__global__ __launch_bounds__(256) void gemm_bt(const unsigned short* __restrict__ A,
                                               const unsigned short* __restrict__ Bt,
                                               void* __restrict__ Cv, int N, int K) {
    __shared__ __align__(16) unsigned short As[128 * 64];
    __shared__ __align__(16) unsigned short Bs[128 * 64];
    const int t = threadIdx.x;
    const int lane = t & 63, w = t >> 6;
    const int wr = w >> 1, wc = w & 1;
    const int lr = lane & 15, lh = lane >> 4;
    const int m0 = blockIdx.y * 128, n0 = blockIdx.x * 128;

    f4v acc[4][4];
    #pragma unroll
    for (int i = 0; i < 4; ++i)
        #pragma unroll
        for (int j = 0; j < 4; ++j) acc[i][j] = f4v{0.f, 0.f, 0.f, 0.f};

    const int o_t = t * 16;
    for (int k0 = 0; k0 < K; k0 += 64) {
        __syncthreads();
        #pragma unroll
        for (int s = 0; s < 4; ++s) {
            int o = s * 4096 + o_t;          // linear LDS byte offset
            int row = o >> 7;
            int src = (o & 127) ^ ((row & 7) << 4);   // inverse-swizzled src col (bytes)
            const unsigned short* gA = A + (size_t)(m0 + row) * K + k0 + (src >> 1);
            GLDS16(gA, As + (o >> 1));
            const unsigned short* gB = Bt + (size_t)(n0 + row) * K + k0 + (src >> 1);
            GLDS16(gB, Bs + (o >> 1));
        }
        __syncthreads();
        #pragma unroll
        for (int kk = 0; kk < 2; ++kk) {
            bf8v af[4], bfr[4];
            #pragma unroll
            for (int mi = 0; mi < 4; ++mi) {
                int row = wr * 64 + mi * 16 + lr;
                int col = (kk * 32 + lh * 8) ^ ((row & 7) << 3);
                af[mi] = *(const bf8v*)(As + row * 64 + col);
            }
            #pragma unroll
            for (int ni = 0; ni < 4; ++ni) {
                int row = wc * 64 + ni * 16 + lr;
                int col = (kk * 32 + lh * 8) ^ ((row & 7) << 3);
                bfr[ni] = *(const bf8v*)(Bs + row * 64 + col);
            }
            #pragma unroll
            for (int mi = 0; mi < 4; ++mi)
                #pragma unroll
                for (int ni = 0; ni < 4; ++ni)
                    acc[mi][ni] = __builtin_amdgcn_mfma_f32_16x16x32_bf16(
                        af[mi], bfr[ni], acc[mi][ni], 0, 0, 0);
        }
    }
    #pragma unroll
    for (int mi = 0; mi < 4; ++mi)
        #pragma unroll
        for (int ni = 0; ni < 4; ++ni)
            #pragma unroll
            for (int r = 0; r < 4; ++r) {
                int row = m0 + wr * 64 + mi * 16 + lh * 4 + r;
                int col = n0 + wc * 64 + ni * 16 + lr;
                float v = acc[mi][ni][r];
                if (OUT_BF16) ((unsigned short*)Cv)[(size_t)row * N + col] = f2bf_n(v);
                else          ((float*)Cv)[(size_t)row * N + col] = v;
            }
}

// ---------- flash attention v12 (verified 207.5us config): (512,4) ----------
// 8-wave / 512-thread blocks, 128-row Q super-tiles, fast-path softmax
// (pe=exp2(sa), no sub/max/shfl), l via MFMA ones-column, PV via 16x16x32
// logical-k relabel. OCCUPANCY RULE (r5/r12/r17, 3x confirmed): this working
// set needs >=128 unified regs/wave; any cap below spills (r17: cap 85 ->
// VGPR 40, WRITE 451MB, 201us). (512,4) = 2 blocks/CU is the only viable
// config for this structure.
__global__ __launch_bounds__(512, 4) void flash_attn(
        const unsigned short* __restrict__ QKV,   // [4096][3072] (Q|K|V cols), K roped
        const unsigned short* __restrict__ VtG,   // [512][4096], group-permuted
        const int* __restrict__ amask,
        const int* __restrict__ pos_ids,
        const unsigned* __restrict__ kmaxp,
        unsigned short* __restrict__ O) {         // [4096][2048]
    __shared__ __align__(16) unsigned short Ks[2][64 * 64];   // K[key][d], swizzled
    __shared__ __align__(16) unsigned short Vs[2][64 * 64];   // V^T[d][key-perm]

    const int t = threadIdx.x, lane = t & 63, w = t >> 6;
    const int lr = lane & 15, lh = lane >> 4;
    const int qsel = w >> 2, w4 = w & 3;
    const int pair = blockIdx.x, h = blockIdx.y, b = blockIdx.z;
    const size_t tok0 = (size_t)b * 2048;

    const unsigned short* Kb = QKV + tok0 * 3072 + 2048 + (h >> 2) * 64;    // row stride 3072
    const unsigned short* Vb = VtG + (size_t)((h >> 2) * 64) * 4096 + tok0; // row stride 4096
    const int* amrow = amask + b * 2048;
    const float kmax = __uint_as_float(*kmaxp);

// 512 threads stage one 64x64 K tile + one 64x64 V tile: 1 chunk each
#define STAGE(buf, kt)                                                              \
    {   int c_ = t;                                                                 \
        int row_ = c_ >> 3;                                                         \
        int sc_ = (((c_ & 7) * 16) ^ ((row_ & 7) << 4)) >> 1;                       \
        GLDS16(Kb + (size_t)((kt) * 64 + row_) * 3072 + sc_, Ks[buf] + c_ * 8);     \
        GLDS16(Vb + (size_t)row_ * 4096 + (kt) * 64 + (c_ & 7) * 8,                 \
               Vs[buf] + c_ * 8);                                                   \
    }

    const float SCL = 0.18033688011112042f;  // (1/sqrt(64)) * log2(e)
    union O8 { bf8v v; unsigned u[4]; };
    O8 ones8;
    ones8.u[0] = ones8.u[1] = ones8.u[2] = ones8.u[3] = 0x3f803f80u;  // 8 x bf16 1.0
    const f4v zf = f4v{0.f, 0.f, 0.f, 0.f};             // hoisted MFMA C=0

    // ---- per-tile aliveness mask, in registers (wave-uniform; no LDS) ----
    unsigned aliveMaskV = 0;
    {
        const int4* am4 = (const int4*)amrow;   // 512 int4s; int4 i covers keys 4i..4i+3
        #pragma unroll
        for (int s = 0; s < 8; ++s) {
            int4 a = am4[s * 64 + lane];
            unsigned long long bal = __ballot(a.x && a.y && a.z && a.w);
            #pragma unroll
            for (int g = 0; g < 4; ++g)
                aliveMaskV |= (((bal >> (16 * g)) & 0xFFFFull) == 0xFFFFull)
                                  ? (1u << (4 * s + g)) : 0u;
        }
    }
    const int aliveMask = __builtin_amdgcn_readfirstlane((int)aliveMaskV);

    // V-read columns (shorts): key-group (kf*4+lh) at permuted position ^lr
    int vcol[4];
    #pragma unroll
    for (int kf = 0; kf < 4; ++kf) vcol[kf] = ((kf * 4 + lh) ^ lr) * 4;

    int cur = 0;
    STAGE(cur, 0);      // tile 0 (shared by both halves' first iteration)

    #pragma unroll 1
    for (int half = 0; half < 2; ++half) {
        const int sj = half ? (15 - pair) : pair;   // super-tile (128 q-rows)
        const int q0 = sj * 128;
        const int nkv = 2 * sj + 2;                 // KV tiles 0..2sj+1
        const int qtw = 2 * sj + qsel;              // this wave's diagonal KV tile
        const int qloc = w4 * 16 + lr;              // q row within wave's 64-row tile

        // ---- load Q row, RoPE in-register (fp32), fold SCL, back to bf16 ----
        const unsigned short* Qp = QKV + (tok0 + q0 + qsel * 64 + qloc) * 3072 + h * 64;
        union Q8 { bf8v v; unsigned short s[8]; } qa0u, qa1u;
        qa0u.v = *(const bf8v*)(Qp + lh * 8);
        qa1u.v = *(const bf8v*)(Qp + 32 + lh * 8);
        float qrmax = 0.f;
        {
            int pos = pos_ids[tok0 + q0 + qsel * 64 + qloc];
            #pragma unroll
            for (int r = 0; r < 4; ++r) {
                float i0 = (float)(lh * 4 + r);
                float ang0 = (float)pos * exp2f(-0.41524101186092f * i0);
                float sn = sinf(ang0), cs = cosf(ang0);
                float xr = bf2f(qa0u.s[2 * r]), xi = bf2f(qa0u.s[2 * r + 1]);
                float a0 = (xr * cs - xi * sn) * SCL, a1 = (xr * sn + xi * cs) * SCL;
                qa0u.s[2 * r]     = f2bf_n(a0);
                qa0u.s[2 * r + 1] = f2bf_n(a1);
                float i1 = (float)(16 + lh * 4 + r);
                float ang1 = (float)pos * exp2f(-0.41524101186092f * i1);
                float sn1 = sinf(ang1), cs1 = cosf(ang1);
                float yr = bf2f(qa1u.s[2 * r]), yi = bf2f(qa1u.s[2 * r + 1]);
                float b0 = (yr * cs1 - yi * sn1) * SCL, b1 = (yr * sn1 + yi * cs1) * SCL;
                qa1u.s[2 * r]     = f2bf_n(b0);
                qa1u.s[2 * r + 1] = f2bf_n(b1);
                qrmax = fmaxf(qrmax, fmaxf(fmaxf(fabsf(a0), fabsf(a1)),
                                           fmaxf(fabsf(b0), fabsf(b1))));
            }
        }
        const bf8v qa0 = qa0u.v, qa1 = qa1u.v;
        // per-q-row score bound: |sa| <= 64 * max|q'| * max|K| (with margins)
        qrmax = fmaxf(qrmax, __shfl_xor(qrmax, 16));
        qrmax = fmaxf(qrmax, __shfl_xor(qrmax, 32));
        const bool safe = __all(64.0f * qrmax * kmax * 1.02f < 80.0f);

        f4v oacc[4];
        #pragma unroll
        for (int i = 0; i < 4; ++i) oacc[i] = f4v{0.f, 0.f, 0.f, 0.f};
        f4v lacc = f4v{0.f, 0.f, 0.f, 0.f};
        float m_ = 0.f;
        f4v sa[4];

        // S^T = K Q^T into sa (reads Ks[curb]); C=0 via hoisted zf (no re-zero)
        auto qk = [&](int curb) {
            __builtin_amdgcn_s_setprio(1);
            #pragma unroll
            for (int kf = 0; kf < 4; ++kf) {
                const unsigned short* Krow = Ks[curb] + (kf * 16 + lr) * 64;
                int swz = (lr & 7) << 3;
                bf8v kb0 = *(const bf8v*)(Krow + ((lh * 8) ^ swz));
                f4v s0 = __builtin_amdgcn_mfma_f32_16x16x32_bf16(kb0, qa0, zf, 0, 0, 0);
                bf8v kb1 = *(const bf8v*)(Krow + ((32 + lh * 8) ^ swz));
                sa[kf] = __builtin_amdgcn_mfma_f32_16x16x32_bf16(kb1, qa1, s0, 0, 0, 0);
            }
            __builtin_amdgcn_s_setprio(0);
        };

        // pack pe per 32-key window, accumulate l via ones-MFMA, PV (16x16x32)
        auto pv = [&](int curb, float pe[4][4]) {
            __builtin_amdgcn_s_setprio(1);
            #pragma unroll
            for (int wdw = 0; wdw < 2; ++wdw) {
                union P8 { bf8v v; unsigned u[4]; } pa;
                pa.u[0] = pack2bf(pe[2 * wdw][0], pe[2 * wdw][1]);
                pa.u[1] = pack2bf(pe[2 * wdw][2], pe[2 * wdw][3]);
                pa.u[2] = pack2bf(pe[2 * wdw + 1][0], pe[2 * wdw + 1][1]);
                pa.u[3] = pack2bf(pe[2 * wdw + 1][2], pe[2 * wdw + 1][3]);
                lacc = __builtin_amdgcn_mfma_f32_16x16x32_bf16(pa.v, ones8.v, lacc, 0, 0, 0);
                #pragma unroll
                for (int df = 0; df < 4; ++df) {
                    const unsigned short* Vrow = Vs[curb] + (df * 16 + lr) * 64;
                    union V8 { bf8v v; uint2 u2[2]; } vb;
                    vb.u2[0] = *(const uint2*)(Vrow + vcol[2 * wdw]);
                    vb.u2[1] = *(const uint2*)(Vrow + vcol[2 * wdw + 1]);
                    oacc[df] = __builtin_amdgcn_mfma_f32_16x16x32_bf16(
                        pa.v, vb.v, oacc[df], 0, 0, 0);
                }
            }
            __builtin_amdgcn_s_setprio(0);
        };

        auto softmax_pv = [&](int curb) {
            float pe[4][4];
            if (__builtin_expect(safe, 1)) {
                // fast: no subtraction, no max logic, no reductions
                #pragma unroll
                for (int kf = 0; kf < 4; ++kf)
                    #pragma unroll
                    for (int r = 0; r < 4; ++r)
                        pe[kf][r] = exp2f(sa[kf][r]);
            } else {
                // slow: lazy-rescale (guarded by row-sum overflow)
                #pragma unroll 1
                for (;;) {
                    #pragma unroll
                    for (int kf = 0; kf < 4; ++kf)
                        #pragma unroll
                        for (int r = 0; r < 4; ++r)
                            pe[kf][r] = exp2f(sa[kf][r] - m_);
                    f2v v0 = f2v{pe[0][0], pe[0][1]} + f2v{pe[0][2], pe[0][3]};
                    f2v v1 = f2v{pe[1][0], pe[1][1]} + f2v{pe[1][2], pe[1][3]};
                    f2v v2 = f2v{pe[2][0], pe[2][1]} + f2v{pe[2][2], pe[2][3]};
                    f2v v3 = f2v{pe[3][0], pe[3][1]} + f2v{pe[3][2], pe[3][3]};
                    f2v vv = (v0 + v1) + (v2 + v3);
                    float rs = vv[0] + vv[1];
                    rs += __shfl_xor(rs, 16);
                    rs += __shfl_xor(rs, 32);
                    if (!__any(rs > 16777216.0f)) break;
                    float t0 = fmaxf(fmaxf(sa[0][0], sa[0][1]), fmaxf(sa[0][2], sa[0][3]));
                    float t1 = fmaxf(fmaxf(sa[1][0], sa[1][1]), fmaxf(sa[1][2], sa[1][3]));
                    float t2 = fmaxf(fmaxf(sa[2][0], sa[2][1]), fmaxf(sa[2][2], sa[2][3]));
                    float t3 = fmaxf(fmaxf(sa[3][0], sa[3][1]), fmaxf(sa[3][2], sa[3][3]));
                    float mx = fmaxf(fmaxf(t0, t1), fmaxf(t2, t3));
                    mx = fmaxf(mx, __shfl_xor(mx, 16));
                    mx = fmaxf(mx, __shfl_xor(mx, 32));
                    float mn = fmaxf(m_, mx);
                    float fac = exp2f(m_ - mn);
                    m_ = mn;
                    float facr[4];
                    #pragma unroll
                    for (int r = 0; r < 4; ++r) facr[r] = __shfl(fac, lh * 4 + r);
                    lacc[0] *= facr[0]; lacc[1] *= facr[1];
                    lacc[2] *= facr[2]; lacc[3] *= facr[3];
                    #pragma unroll
                    for (int df = 0; df < 4; ++df) {
                        f4v o = oacc[df];
                        o[0] *= facr[0]; o[1] *= facr[1]; o[2] *= facr[2]; o[3] *= facr[3];
                        oacc[df] = o;
                    }
                }
            }
            pv(curb, pe);
        };

        __syncthreads();   // tile (cur) staged & previous reads done

        // ---- KV loop over tiles 0..2sj+1 ----
        #pragma unroll 1
        for (int kt = 0; kt < nkv; ++kt) {
            if (kt + 1 < nkv) STAGE(cur ^ 1, kt + 1)
            else if (half == 0) STAGE(cur ^ 1, 0)     // cross-half tile-0 prefetch

            if (kt <= qtw) {                          // wave-uniform branch
                qk(cur);
                if (kt == qtw) {
                    // diagonal tile for this wave (causal + padding)
                    if ((aliveMask >> kt) & 1) {
                        #pragma unroll
                        for (int kf = 0; kf < 4; ++kf)
                            #pragma unroll
                            for (int r = 0; r < 4; ++r) {
                                int keyl = kf * 16 + lh * 4 + r;
                                if (keyl > qloc) sa[kf][r] = -1e30f;
                            }
                    } else {
                        #pragma unroll
                        for (int kf = 0; kf < 4; ++kf) {
                            int4 aq = *(const int4*)(amrow + kt * 64 + kf * 16 + lh * 4);
                            #pragma unroll
                            for (int r = 0; r < 4; ++r) {
                                int keyl = kf * 16 + lh * 4 + r;
                                int am = r == 0 ? aq.x : r == 1 ? aq.y : r == 2 ? aq.z : aq.w;
                                if (am == 0 || keyl > qloc) sa[kf][r] = -1e30f;
                            }
                        }
                    }
                } else if (!((aliveMask >> kt) & 1)) {   // rare: padding mask
                    #pragma unroll
                    for (int kf = 0; kf < 4; ++kf) {
                        int4 aq = *(const int4*)(amrow + kt * 64 + kf * 16 + lh * 4);
                        if (aq.x == 0) sa[kf][0] = -1e30f;
                        if (aq.y == 0) sa[kf][1] = -1e30f;
                        if (aq.z == 0) sa[kf][2] = -1e30f;
                        if (aq.w == 0) sa[kf][3] = -1e30f;
                    }
                }
                softmax_pv(cur);
            }

            __syncthreads();   // drains prefetch vmcnt + joins waves
            cur ^= 1;
        }

        // ---- epilogue: normalize, write bf16 [tok][2048] ----
        // lacc rows == oacc rows (q = lh*4+r) -> no cross-lane redistribution
        float invr[4];
        #pragma unroll
        for (int r = 0; r < 4; ++r) invr[r] = 1.0f / lacc[r];
        #pragma unroll
        for (int df = 0; df < 4; ++df)
            #pragma unroll
            for (int r = 0; r < 4; ++r) {
                int qg = q0 + qsel * 64 + w4 * 16 + lh * 4 + r;
                float v = oacc[df][r] * invr[r];
                O[(tok0 + qg) * 2048 + h * 64 + df * 16 + lr] = f2bf_n(v);
            }
    }
#undef STAGE
}

// ---------- launch ----------
extern "C" void kernel_launch(void* const* d_in, const int* in_sizes, int n_in,
                              void* d_out, int out_size, void* d_ws, size_t ws_size,
                              hipStream_t stream) {
    const float* hs   = (const float*)d_in[0];
    const int* amask  = (const int*)d_in[1];
    const int* pos    = (const int*)d_in[2];
    const float* wq   = (const float*)d_in[3];
    const float* wk   = (const float*)d_in[4];
    const float* wv   = (const float*)d_in[5];
    const float* wo   = (const float*)d_in[6];

    char* ws = (char*)d_ws;
    unsigned short* Xb   = (unsigned short*)(ws);             // 16,777,216 B
    unsigned short* Wqkv = (unsigned short*)(ws + 16777216);  // 12,582,912  [3072][2048]
    unsigned short* Wot  = (unsigned short*)(ws + 29360128);  //  8,388,608
    unsigned short* AOb  = (unsigned short*)(ws + 37748736);  // 16,777,216 (ends 54,525,952)
    unsigned* kmaxp      = (unsigned*)(ws);                   // reuses Xb (dead after QKV gemm)
    float* kpart         = (float*)(ws + 1024);               // 16384 floats, also in dead Xb

    // QKV bf16 [4096][3072] + VtG [512][4096] live inside d_out (dead before final GEMM)
    char* ob = (char*)d_out;
    unsigned short* QKV = (unsigned short*)ob;                // 25,165,824
    unsigned short* VtG = (unsigned short*)(ob + 25165824);   //  4,194,304 (ends 29,360,128)

    // fused prep: X cast + 4 weight transposes in one launch
    prep_all<<<14336, 256, 0, stream>>>(hs, Xb, wq, wk, wv, wo, Wqkv, Wot);

    // fused QKV projection: [4096][3072]
    gemm_bt<1><<<dim3(24, 32), 256, 0, stream>>>(Xb, Wqkv, (void*)QKV, 3072, 2048);

    // fused: K RoPE (per-wave max -> kpart) + V transpose (independent columns)
    rope_tv<<<6144, 256, 0, stream>>>(QKV, pos, kpart, VtG);
    reduce_kmax<<<1, 256, 0, stream>>>(kpart, kmaxp);

    flash_attn<<<dim3(8, 32, 2), 512, 0, stream>>>(QKV, VtG, amask, pos, kmaxp, AOb);

    gemm_bt<0><<<dim3(16, 32), 256, 0, stream>>>(AOb, Wot, d_out, 2048, 2048);
}

// Round 19
// 207.416 us; speedup vs baseline: 1.4602x; 1.0020x over previous
//
#include <hip/hip_runtime.h>
#include <cstdint>

// ---------- types ----------
typedef __attribute__((ext_vector_type(8))) __bf16  bf8v;   // MFMA A/B operand (4 VGPRs)
typedef __attribute__((ext_vector_type(4))) float   f4v;    // MFMA C/D
typedef __attribute__((ext_vector_type(2))) float   f2v;    // packed f32 pair
typedef __attribute__((ext_vector_type(8))) unsigned short ush8; // 16B staging chunk

__device__ __forceinline__ float bf2f(unsigned short u) {
    union { unsigned u; float f; } v; v.u = ((unsigned)u) << 16; return v.f;
}
// native HW converts (RNE) — compiler emits v_cvt(_pk)_bf16_f32
__device__ __forceinline__ unsigned short f2bf_n(float f) {
    union { __bf16 h; unsigned short s; } v; v.h = (__bf16)f; return v.s;
}
__device__ __forceinline__ unsigned pack2bf(float a, float b) {
    union { __bf16 h[2]; unsigned u; } v;
    v.h[0] = (__bf16)a; v.h[1] = (__bf16)b; return v.u;
}

#define GLDS16(gp, lp)                                                          \
    __builtin_amdgcn_global_load_lds(                                           \
        (const __attribute__((address_space(1))) void*)(uintptr_t)(gp),         \
        (__attribute__((address_space(3))) void*)(uintptr_t)(lp), 16, 0, 0)

// ---------- fused prep: X cast (blocks 0..4095) + 4 weight transposes ----------
__global__ void prep_all(const float* __restrict__ hs, unsigned short* __restrict__ Xb,
                         const float* __restrict__ wq, const float* __restrict__ wk,
                         const float* __restrict__ wv, const float* __restrict__ wo,
                         unsigned short* __restrict__ Wqkv, unsigned short* __restrict__ Wot) {
    const int blk = blockIdx.x;
    if (blk < 4096) {                    // ---- cast X fp32 -> bf16, 8 elems/thread
        int i = blk * 256 + threadIdx.x;
        float4 a = ((const float4*)hs)[2 * i];
        float4 b = ((const float4*)hs)[2 * i + 1];
        uint4 o;
        o.x = pack2bf(a.x, a.y);
        o.y = pack2bf(a.z, a.w);
        o.z = pack2bf(b.x, b.y);
        o.w = pack2bf(b.z, b.w);
        ((uint4*)Xb)[i] = o;
        return;                          // block-uniform branch: no barrier hazard
    }
    const float* in;
    unsigned short* out;
    int C, bx, by;
    if (blk < 8192)       { int z = blk - 4096;  in = wq; out = Wqkv;           C = 2048; bx = z & 63; by = z >> 6; }
    else if (blk < 9216)  { int z = blk - 8192;  in = wk; out = Wqkv + 4194304; C = 512;  bx = z & 15; by = z >> 4; }
    else if (blk < 10240) { int z = blk - 9216;  in = wv; out = Wqkv + 5242880; C = 512;  bx = z & 15; by = z >> 4; }
    else                  { int z = blk - 10240; in = wo; out = Wot;            C = 2048; bx = z & 63; by = z >> 6; }
    __shared__ float t[32][33];
    const int c0 = bx * 32, r0 = by * 32;
    const int x = threadIdx.x & 31, y = threadIdx.x >> 5;   // (32,8) layout
    #pragma unroll
    for (int i = 0; i < 32; i += 8) t[y + i][x] = in[(size_t)(r0 + y + i) * C + c0 + x];
    __syncthreads();
    #pragma unroll
    for (int i = 0; i < 32; i += 8)
        out[(size_t)(c0 + y + i) * 2048 + r0 + x] = f2bf_n(t[x][y + i]);   // R = 2048 always
}

// ---------- fused: K RoPE (blocks 0..4095) + V transpose (blocks 4096..6143) ----------
__global__ void rope_tv(unsigned short* __restrict__ QKV,
                        const int* __restrict__ pos_ids,
                        float* __restrict__ kpart,
                        unsigned short* __restrict__ VtG) {
    const int blk = blockIdx.x;
    if (blk < 4096) {
        // ---- K RoPE in place (8 kv heads, stride 3072, coloff 2048) ----
        int idx = blk * 256 + threadIdx.x;
        int i   = idx & 31;                   // pair index (D/2 = 32)
        int hh  = (idx >> 5) & 7;             // nh_log2 = 3
        int tok = idx >> 8;
        int pos = pos_ids[tok];
        float ang = (float)pos * exp2f(-0.41524101186092f * (float)i);
        float s = sinf(ang), c = cosf(ang);
        unsigned short* p = QKV + (size_t)tok * 3072 + 2048 + hh * 64 + 2 * i;
        unsigned pr = *(const unsigned*)p;
        float xr = bf2f((unsigned short)(pr & 0xffff));
        float xi = bf2f((unsigned short)(pr >> 16));
        float orr = xr * c - xi * s;
        float oi  = xr * s + xi * c;
        *(unsigned*)p = pack2bf(orr, oi);
        // per-wave max|K| -> plain store (NO same-address atomics: r9 lesson)
        float loc = fmaxf(fabsf(orr), fabsf(oi));
        #pragma unroll
        for (int off = 1; off < 64; off <<= 1) loc = fmaxf(loc, __shfl_xor(loc, off));
        if ((threadIdx.x & 63) == 0) kpart[blk * 4 + (threadIdx.x >> 6)] = loc;
        return;
    }
    // ---- V transpose with key-group XOR permutation: [4096][3072]@2560 -> [512][4096]
    __shared__ unsigned short t[32][33];
    const int z = blk - 4096;                 // grid was (16,128)
    const int c0 = (z & 15) * 32;             // v-col d
    const int r0 = (z >> 4) * 32;             // token
    const int x = threadIdx.x & 31, y = threadIdx.x >> 5;
    #pragma unroll
    for (int i = 0; i < 32; i += 8)
        t[y + i][x] = QKV[(size_t)(r0 + y + i) * 3072 + 2560 + c0 + x];
    __syncthreads();
    #pragma unroll
    for (int i = 0; i < 32; i += 8) {
        int d   = c0 + y + i;
        int tok = r0 + x;
        int g   = (tok >> 2) & 15;
        int tp  = (tok & ~63) | (((g ^ (d & 15)) << 2)) | (tok & 3);
        VtG[(size_t)d * 4096 + tp] = t[x][y + i];
    }
}

// ---------- single-block reduce of 16384 partial maxima -> kmax scalar ----------
__global__ void reduce_kmax(const float* __restrict__ kpart,
                            unsigned* __restrict__ kmax_out) {
    float loc = 0.f;
    #pragma unroll
    for (int i = 0; i < 16; ++i) {
        float4 v = ((const float4*)kpart)[i * 256 + threadIdx.x];
        loc = fmaxf(loc, fmaxf(fmaxf(v.x, v.y), fmaxf(v.z, v.w)));
    }
    #pragma unroll
    for (int off = 1; off < 64; off <<= 1) loc = fmaxf(loc, __shfl_xor(loc, off));
    __shared__ float warr[4];
    if ((threadIdx.x & 63) == 0) warr[threadIdx.x >> 6] = loc;
    __syncthreads();
    if (threadIdx.x == 0)
        *kmax_out = __float_as_uint(fmaxf(fmaxf(warr[0], warr[1]),
                                          fmaxf(warr[2], warr[3])));
}

// ---------- GEMM: C[M][N] = A[M][K] * Bt[N][K]^T  (bf16 in, fp32 acc) ----------
template <int OUT_BF16>
__global__ __launch_bounds__(256) void gemm_bt(const unsigned short* __restrict__ A,
                                               const unsigned short* __restrict__ Bt,
                                               void* __restrict__ Cv, int N, int K) {
    __shared__ __align__(16) unsigned short As[128 * 64];
    __shared__ __align__(16) unsigned short Bs[128 * 64];
    const int t = threadIdx.x;
    const int lane = t & 63, w = t >> 6;
    const int wr = w >> 1, wc = w & 1;
    const int lr = lane & 15, lh = lane >> 4;
    const int m0 = blockIdx.y * 128, n0 = blockIdx.x * 128;

    f4v acc[4][4];
    #pragma unroll
    for (int i = 0; i < 4; ++i)
        #pragma unroll
        for (int j = 0; j < 4; ++j) acc[i][j] = f4v{0.f, 0.f, 0.f, 0.f};

    const int o_t = t * 16;
    for (int k0 = 0; k0 < K; k0 += 64) {
        __syncthreads();
        #pragma unroll
        for (int s = 0; s < 4; ++s) {
            int o = s * 4096 + o_t;          // linear LDS byte offset
            int row = o >> 7;
            int src = (o & 127) ^ ((row & 7) << 4);   // inverse-swizzled src col (bytes)
            const unsigned short* gA = A + (size_t)(m0 + row) * K + k0 + (src >> 1);
            GLDS16(gA, As + (o >> 1));
            const unsigned short* gB = Bt + (size_t)(n0 + row) * K + k0 + (src >> 1);
            GLDS16(gB, Bs + (o >> 1));
        }
        __syncthreads();
        #pragma unroll
        for (int kk = 0; kk < 2; ++kk) {
            bf8v af[4], bfr[4];
            #pragma unroll
            for (int mi = 0; mi < 4; ++mi) {
                int row = wr * 64 + mi * 16 + lr;
                int col = (kk * 32 + lh * 8) ^ ((row & 7) << 3);
                af[mi] = *(const bf8v*)(As + row * 64 + col);
            }
            #pragma unroll
            for (int ni = 0; ni < 4; ++ni) {
                int row = wc * 64 + ni * 16 + lr;
                int col = (kk * 32 + lh * 8) ^ ((row & 7) << 3);
                bfr[ni] = *(const bf8v*)(Bs + row * 64 + col);
            }
            #pragma unroll
            for (int mi = 0; mi < 4; ++mi)
                #pragma unroll
                for (int ni = 0; ni < 4; ++ni)
                    acc[mi][ni] = __builtin_amdgcn_mfma_f32_16x16x32_bf16(
                        af[mi], bfr[ni], acc[mi][ni], 0, 0, 0);
        }
    }
    #pragma unroll
    for (int mi = 0; mi < 4; ++mi)
        #pragma unroll
        for (int ni = 0; ni < 4; ++ni)
            #pragma unroll
            for (int r = 0; r < 4; ++r) {
                int row = m0 + wr * 64 + mi * 16 + lh * 4 + r;
                int col = n0 + wc * 64 + ni * 16 + lr;
                float v = acc[mi][ni][r];
                if (OUT_BF16) ((unsigned short*)Cv)[(size_t)row * N + col] = f2bf_n(v);
                else          ((float*)Cv)[(size_t)row * N + col] = v;
            }
}

// ---------- flash attention v13: 128-key KV tiles (barriers halved) ----------
// v12 structure with KV-tile = 128 keys per barrier pair: LDS [2][2x64x64]
// (64KB, still 2 blocks/CU); each 128-tile staged as TWO byte-identical
// copies of the verified 64-key STAGE at sub-tile offsets 0/4096; compute
// body runs twice per barrier with only an LDS base offset. Barriers/block:
// 35 -> 18. OCCUPANCY RULE (r5/r12/r17): needs >=128 unified regs/wave;
// (512,4) is the only viable config.
__global__ __launch_bounds__(512, 4) void flash_attn(
        const unsigned short* __restrict__ QKV,   // [4096][3072] (Q|K|V cols), K roped
        const unsigned short* __restrict__ VtG,   // [512][4096], group-permuted
        const int* __restrict__ amask,
        const int* __restrict__ pos_ids,
        const unsigned* __restrict__ kmaxp,
        unsigned short* __restrict__ O) {         // [4096][2048]
    __shared__ __align__(16) unsigned short Ks[2][2 * 64 * 64];  // K[key][d], swizzled
    __shared__ __align__(16) unsigned short Vs[2][2 * 64 * 64];  // V^T[d][key-perm]

    const int t = threadIdx.x, lane = t & 63, w = t >> 6;
    const int lr = lane & 15, lh = lane >> 4;
    const int qsel = w >> 2, w4 = w & 3;
    const int pair = blockIdx.x, h = blockIdx.y, b = blockIdx.z;
    const size_t tok0 = (size_t)b * 2048;

    const unsigned short* Kb = QKV + tok0 * 3072 + 2048 + (h >> 2) * 64;    // row stride 3072
    const unsigned short* Vb = VtG + (size_t)((h >> 2) * 64) * 4096 + tok0; // row stride 4096
    const int* amrow = amask + b * 2048;
    const float kmax = __uint_as_float(*kmaxp);

// stage one 64-key sub-tile (identical addressing to verified v12 STAGE)
#define STAGE1(buf, st, kt64)                                                        \
    {   int c_ = t;                                                                  \
        int row_ = c_ >> 3;                                                          \
        int sc_ = (((c_ & 7) * 16) ^ ((row_ & 7) << 4)) >> 1;                        \
        GLDS16(Kb + (size_t)((kt64) * 64 + row_) * 3072 + sc_,                       \
               Ks[buf] + (st) * 4096 + c_ * 8);                                      \
        GLDS16(Vb + (size_t)row_ * 4096 + (kt64) * 64 + (c_ & 7) * 8,                \
               Vs[buf] + (st) * 4096 + c_ * 8);                                      \
    }
#define STAGE128(buf, kt128) { STAGE1(buf, 0, 2 * (kt128)) STAGE1(buf, 1, 2 * (kt128) + 1) }

    const float SCL = 0.18033688011112042f;  // (1/sqrt(64)) * log2(e)
    union O8 { bf8v v; unsigned u[4]; };
    O8 ones8;
    ones8.u[0] = ones8.u[1] = ones8.u[2] = ones8.u[3] = 0x3f803f80u;  // 8 x bf16 1.0
    const f4v zf = f4v{0.f, 0.f, 0.f, 0.f};             // hoisted MFMA C=0

    // ---- per-tile aliveness mask, in registers (wave-uniform; no LDS) ----
    unsigned aliveMaskV = 0;
    {
        const int4* am4 = (const int4*)amrow;   // 512 int4s; int4 i covers keys 4i..4i+3
        #pragma unroll
        for (int s = 0; s < 8; ++s) {
            int4 a = am4[s * 64 + lane];
            unsigned long long bal = __ballot(a.x && a.y && a.z && a.w);
            #pragma unroll
            for (int g = 0; g < 4; ++g)
                aliveMaskV |= (((bal >> (16 * g)) & 0xFFFFull) == 0xFFFFull)
                                  ? (1u << (4 * s + g)) : 0u;
        }
    }
    const int aliveMask = __builtin_amdgcn_readfirstlane((int)aliveMaskV);

    // V-read columns (shorts): key-group (kf*4+lh) at permuted position ^lr
    int vcol[4];
    #pragma unroll
    for (int kf = 0; kf < 4; ++kf) vcol[kf] = ((kf * 4 + lh) ^ lr) * 4;

    int cur = 0;
    STAGE128(cur, 0);      // 128-key tile 0 (shared by both halves' first iteration)

    #pragma unroll 1
    for (int half = 0; half < 2; ++half) {
        const int sj = half ? (15 - pair) : pair;   // super-tile (128 q-rows)
        const int q0 = sj * 128;
        const int nkv = sj + 1;                     // 128-key tiles 0..sj
        const int qtw = 2 * sj + qsel;              // this wave's diagonal 64-key tile
        const int qloc = w4 * 16 + lr;              // q row within wave's 64-row tile

        // ---- load Q row, RoPE in-register (fp32), fold SCL, back to bf16 ----
        const unsigned short* Qp = QKV + (tok0 + q0 + qsel * 64 + qloc) * 3072 + h * 64;
        union Q8 { bf8v v; unsigned short s[8]; } qa0u, qa1u;
        qa0u.v = *(const bf8v*)(Qp + lh * 8);
        qa1u.v = *(const bf8v*)(Qp + 32 + lh * 8);
        float qrmax = 0.f;
        {
            int pos = pos_ids[tok0 + q0 + qsel * 64 + qloc];
            #pragma unroll
            for (int r = 0; r < 4; ++r) {
                float i0 = (float)(lh * 4 + r);
                float ang0 = (float)pos * exp2f(-0.41524101186092f * i0);
                float sn = sinf(ang0), cs = cosf(ang0);
                float xr = bf2f(qa0u.s[2 * r]), xi = bf2f(qa0u.s[2 * r + 1]);
                float a0 = (xr * cs - xi * sn) * SCL, a1 = (xr * sn + xi * cs) * SCL;
                qa0u.s[2 * r]     = f2bf_n(a0);
                qa0u.s[2 * r + 1] = f2bf_n(a1);
                float i1 = (float)(16 + lh * 4 + r);
                float ang1 = (float)pos * exp2f(-0.41524101186092f * i1);
                float sn1 = sinf(ang1), cs1 = cosf(ang1);
                float yr = bf2f(qa1u.s[2 * r]), yi = bf2f(qa1u.s[2 * r + 1]);
                float b0 = (yr * cs1 - yi * sn1) * SCL, b1 = (yr * sn1 + yi * cs1) * SCL;
                qa1u.s[2 * r]     = f2bf_n(b0);
                qa1u.s[2 * r + 1] = f2bf_n(b1);
                qrmax = fmaxf(qrmax, fmaxf(fmaxf(fabsf(a0), fabsf(a1)),
                                           fmaxf(fabsf(b0), fabsf(b1))));
            }
        }
        const bf8v qa0 = qa0u.v, qa1 = qa1u.v;
        // per-q-row score bound: |sa| <= 64 * max|q'| * max|K| (with margins)
        qrmax = fmaxf(qrmax, __shfl_xor(qrmax, 16));
        qrmax = fmaxf(qrmax, __shfl_xor(qrmax, 32));
        const bool safe = __all(64.0f * qrmax * kmax * 1.02f < 80.0f);

        f4v oacc[4];
        #pragma unroll
        for (int i = 0; i < 4; ++i) oacc[i] = f4v{0.f, 0.f, 0.f, 0.f};
        f4v lacc = f4v{0.f, 0.f, 0.f, 0.f};
        float m_ = 0.f;
        f4v sa[4];

        // S^T = K Q^T into sa from Ks[curb] sub-tile st; C=0 via hoisted zf
        auto qk = [&](int curb, int st) {
            const unsigned short* Kbase = Ks[curb] + st * 4096;
            __builtin_amdgcn_s_setprio(1);
            #pragma unroll
            for (int kf = 0; kf < 4; ++kf) {
                const unsigned short* Krow = Kbase + (kf * 16 + lr) * 64;
                int swz = (lr & 7) << 3;
                bf8v kb0 = *(const bf8v*)(Krow + ((lh * 8) ^ swz));
                f4v s0 = __builtin_amdgcn_mfma_f32_16x16x32_bf16(kb0, qa0, zf, 0, 0, 0);
                bf8v kb1 = *(const bf8v*)(Krow + ((32 + lh * 8) ^ swz));
                sa[kf] = __builtin_amdgcn_mfma_f32_16x16x32_bf16(kb1, qa1, s0, 0, 0, 0);
            }
            __builtin_amdgcn_s_setprio(0);
        };

        // pack pe per 32-key window, accumulate l via ones-MFMA, PV (16x16x32)
        auto pv = [&](int curb, int st, float pe[4][4]) {
            const unsigned short* Vbase = Vs[curb] + st * 4096;
            __builtin_amdgcn_s_setprio(1);
            #pragma unroll
            for (int wdw = 0; wdw < 2; ++wdw) {
                union P8 { bf8v v; unsigned u[4]; } pa;
                pa.u[0] = pack2bf(pe[2 * wdw][0], pe[2 * wdw][1]);
                pa.u[1] = pack2bf(pe[2 * wdw][2], pe[2 * wdw][3]);
                pa.u[2] = pack2bf(pe[2 * wdw + 1][0], pe[2 * wdw + 1][1]);
                pa.u[3] = pack2bf(pe[2 * wdw + 1][2], pe[2 * wdw + 1][3]);
                lacc = __builtin_amdgcn_mfma_f32_16x16x32_bf16(pa.v, ones8.v, lacc, 0, 0, 0);
                #pragma unroll
                for (int df = 0; df < 4; ++df) {
                    const unsigned short* Vrow = Vbase + (df * 16 + lr) * 64;
                    union V8 { bf8v v; uint2 u2[2]; } vb;
                    vb.u2[0] = *(const uint2*)(Vrow + vcol[2 * wdw]);
                    vb.u2[1] = *(const uint2*)(Vrow + vcol[2 * wdw + 1]);
                    oacc[df] = __builtin_amdgcn_mfma_f32_16x16x32_bf16(
                        pa.v, vb.v, oacc[df], 0, 0, 0);
                }
            }
            __builtin_amdgcn_s_setprio(0);
        };

        auto softmax_pv = [&](int curb, int st) {
            float pe[4][4];
            if (__builtin_expect(safe, 1)) {
                // fast: no subtraction, no max logic, no reductions
                #pragma unroll
                for (int kf = 0; kf < 4; ++kf)
                    #pragma unroll
                    for (int r = 0; r < 4; ++r)
                        pe[kf][r] = exp2f(sa[kf][r]);
            } else {
                // slow: lazy-rescale (guarded by row-sum overflow)
                #pragma unroll 1
                for (;;) {
                    #pragma unroll
                    for (int kf = 0; kf < 4; ++kf)
                        #pragma unroll
                        for (int r = 0; r < 4; ++r)
                            pe[kf][r] = exp2f(sa[kf][r] - m_);
                    f2v v0 = f2v{pe[0][0], pe[0][1]} + f2v{pe[0][2], pe[0][3]};
                    f2v v1 = f2v{pe[1][0], pe[1][1]} + f2v{pe[1][2], pe[1][3]};
                    f2v v2 = f2v{pe[2][0], pe[2][1]} + f2v{pe[2][2], pe[2][3]};
                    f2v v3 = f2v{pe[3][0], pe[3][1]} + f2v{pe[3][2], pe[3][3]};
                    f2v vv = (v0 + v1) + (v2 + v3);
                    float rs = vv[0] + vv[1];
                    rs += __shfl_xor(rs, 16);
                    rs += __shfl_xor(rs, 32);
                    if (!__any(rs > 16777216.0f)) break;
                    float t0 = fmaxf(fmaxf(sa[0][0], sa[0][1]), fmaxf(sa[0][2], sa[0][3]));
                    float t1 = fmaxf(fmaxf(sa[1][0], sa[1][1]), fmaxf(sa[1][2], sa[1][3]));
                    float t2 = fmaxf(fmaxf(sa[2][0], sa[2][1]), fmaxf(sa[2][2], sa[2][3]));
                    float t3 = fmaxf(fmaxf(sa[3][0], sa[3][1]), fmaxf(sa[3][2], sa[3][3]));
                    float mx = fmaxf(fmaxf(t0, t1), fmaxf(t2, t3));
                    mx = fmaxf(mx, __shfl_xor(mx, 16));
                    mx = fmaxf(mx, __shfl_xor(mx, 32));
                    float mn = fmaxf(m_, mx);
                    float fac = exp2f(m_ - mn);
                    m_ = mn;
                    float facr[4];
                    #pragma unroll
                    for (int r = 0; r < 4; ++r) facr[r] = __shfl(fac, lh * 4 + r);
                    lacc[0] *= facr[0]; lacc[1] *= facr[1];
                    lacc[2] *= facr[2]; lacc[3] *= facr[3];
                    #pragma unroll
                    for (int df = 0; df < 4; ++df) {
                        f4v o = oacc[df];
                        o[0] *= facr[0]; o[1] *= facr[1]; o[2] *= facr[2]; o[3] *= facr[3];
                        oacc[df] = o;
                    }
                }
            }
            pv(curb, st, pe);
        };

        __syncthreads();   // tile (cur) staged & previous reads done

        // ---- KV loop over 128-key tiles 0..sj ----
        #pragma unroll 1
        for (int kt = 0; kt < nkv; ++kt) {
            if (kt + 1 < nkv) STAGE128(cur ^ 1, kt + 1)
            else if (half == 0) STAGE128(cur ^ 1, 0)   // cross-half tile-0 prefetch

            #pragma unroll
            for (int st = 0; st < 2; ++st) {
                const int kt64 = 2 * kt + st;
                if (kt64 <= qtw) {                     // wave-uniform branch
                    qk(cur, st);
                    if (kt64 == qtw) {
                        // diagonal tile for this wave (causal + padding)
                        if ((aliveMask >> kt64) & 1) {
                            #pragma unroll
                            for (int kf = 0; kf < 4; ++kf)
                                #pragma unroll
                                for (int r = 0; r < 4; ++r) {
                                    int keyl = kf * 16 + lh * 4 + r;
                                    if (keyl > qloc) sa[kf][r] = -1e30f;
                                }
                        } else {
                            #pragma unroll
                            for (int kf = 0; kf < 4; ++kf) {
                                int4 aq = *(const int4*)(amrow + kt64 * 64 + kf * 16 + lh * 4);
                                #pragma unroll
                                for (int r = 0; r < 4; ++r) {
                                    int keyl = kf * 16 + lh * 4 + r;
                                    int am = r == 0 ? aq.x : r == 1 ? aq.y : r == 2 ? aq.z : aq.w;
                                    if (am == 0 || keyl > qloc) sa[kf][r] = -1e30f;
                                }
                            }
                        }
                    } else if (!((aliveMask >> kt64) & 1)) {   // rare: padding mask
                        #pragma unroll
                        for (int kf = 0; kf < 4; ++kf) {
                            int4 aq = *(const int4*)(amrow + kt64 * 64 + kf * 16 + lh * 4);
                            if (aq.x == 0) sa[kf][0] = -1e30f;
                            if (aq.y == 0) sa[kf][1] = -1e30f;
                            if (aq.z == 0) sa[kf][2] = -1e30f;
                            if (aq.w == 0) sa[kf][3] = -1e30f;
                        }
                    }
                    softmax_pv(cur, st);
                }
            }

            __syncthreads();   // drains prefetch vmcnt + joins waves
            cur ^= 1;
        }

        // ---- epilogue: normalize, write bf16 [tok][2048] ----
        // lacc rows == oacc rows (q = lh*4+r) -> no cross-lane redistribution
        float invr[4];
        #pragma unroll
        for (int r = 0; r < 4; ++r) invr[r] = 1.0f / lacc[r];
        #pragma unroll
        for (int df = 0; df < 4; ++df)
            #pragma unroll
            for (int r = 0; r < 4; ++r) {
                int qg = q0 + qsel * 64 + w4 * 16 + lh * 4 + r;
                float v = oacc[df][r] * invr[r];
                O[(tok0 + qg) * 2048 + h * 64 + df * 16 + lr] = f2bf_n(v);
            }
    }
#undef STAGE1
#undef STAGE128
}

// ---------- launch ----------
extern "C" void kernel_launch(void* const* d_in, const int* in_sizes, int n_in,
                              void* d_out, int out_size, void* d_ws, size_t ws_size,
                              hipStream_t stream) {
    const float* hs   = (const float*)d_in[0];
    const int* amask  = (const int*)d_in[1];
    const int* pos    = (const int*)d_in[2];
    const float* wq   = (const float*)d_in[3];
    const float* wk   = (const float*)d_in[4];
    const float* wv   = (const float*)d_in[5];
    const float* wo   = (const float*)d_in[6];

    char* ws = (char*)d_ws;
    unsigned short* Xb   = (unsigned short*)(ws);             // 16,777,216 B
    unsigned short* Wqkv = (unsigned short*)(ws + 16777216);  // 12,582,912  [3072][2048]
    unsigned short* Wot  = (unsigned short*)(ws + 29360128);  //  8,388,608
    unsigned short* AOb  = (unsigned short*)(ws + 37748736);  // 16,777,216 (ends 54,525,952)
    unsigned* kmaxp      = (unsigned*)(ws);                   // reuses Xb (dead after QKV gemm)
    float* kpart         = (float*)(ws + 1024);               // 16384 floats, also in dead Xb

    // QKV bf16 [4096][3072] + VtG [512][4096] live inside d_out (dead before final GEMM)
    char* ob = (char*)d_out;
    unsigned short* QKV = (unsigned short*)ob;                // 25,165,824
    unsigned short* VtG = (unsigned short*)(ob + 25165824);   //  4,194,304 (ends 29,360,128)

    // fused prep: X cast + 4 weight transposes in one launch
    prep_all<<<14336, 256, 0, stream>>>(hs, Xb, wq, wk, wv, wo, Wqkv, Wot);

    // fused QKV projection: [4096][3072]
    gemm_bt<1><<<dim3(24, 32), 256, 0, stream>>>(Xb, Wqkv, (void*)QKV, 3072, 2048);

    // fused: K RoPE (per-wave max -> kpart) + V transpose (independent columns)
    rope_tv<<<6144, 256, 0, stream>>>(QKV, pos, kpart, VtG);
    reduce_kmax<<<1, 256, 0, stream>>>(kpart, kmaxp);

    flash_attn<<<dim3(8, 32, 2), 512, 0, stream>>>(QKV, VtG, amask, pos, kmaxp, AOb);

    gemm_bt<0><<<dim3(16, 32), 256, 0, stream>>>(AOb, Wot, d_out, 2048, 2048);
}